// Round 6
// baseline (657.240 us; speedup 1.0000x reference)
//
#include <hip/hip_runtime.h>

#define N_NODES 100000
#define N_EDGES 600000
#define DIM 128

typedef unsigned short ushortT;
typedef __attribute__((ext_vector_type(8))) short short8;
typedef __attribute__((ext_vector_type(4))) float float4v;
typedef __attribute__((ext_vector_type(4))) unsigned int uint4v;

__device__ __forceinline__ float bf2f(ushortT h) {
    return __builtin_bit_cast(float, ((unsigned int)h) << 16);
}
__device__ __forceinline__ float bflo(unsigned int p) {
    return __builtin_bit_cast(float, p << 16);
}
__device__ __forceinline__ float bfhi(unsigned int p) {
    return __builtin_bit_cast(float, p & 0xffff0000u);
}
__device__ __forceinline__ ushortT f2bf(float f) {  // RNE
    unsigned int x = __builtin_bit_cast(unsigned int, f);
    unsigned int r = (x + 0x7fffu + ((x >> 16) & 1u)) >> 16;
    return (ushortT)r;
}

// ---- prep: W (128x128 f32, KxN) -> transposed + XOR-swizzled bf16 hi/lo images
// element (k,n) stored at  n*128 + (((k>>3) ^ (n&15))<<3) + (k&7)
__global__ __launch_bounds__(256) void prep_kernel(const float* __restrict__ W1,
                                                   const float* __restrict__ W2,
                                                   ushortT* __restrict__ wt) {
    const float* Wf = (blockIdx.x == 0) ? W1 : W2;
    ushortT* outh = wt + blockIdx.x * 32768;
    ushortT* outl = outh + 16384;
    int t = threadIdx.x;
#pragma unroll
    for (int i = 0; i < 16; i++) {
        int c = t + i * 256;            // 0..4095
        int k = c >> 5;
        int n0 = (c & 31) * 4;
        float4v w = *(const float4v*)(Wf + k * 128 + n0);
        int g = k >> 3, kk = k & 7;
#pragma unroll
        for (int j = 0; j < 4; j++) {
            int n = n0 + j;
            ushortT wh = f2bf(w[j]);
            ushortT wl = f2bf(w[j] - bf2f(wh));
            int addr = n * 128 + ((g ^ (n & 15)) << 3) + kk;
            outh[addr] = wh;
            outl[addr] = wl;
        }
    }
}

// ---- x (f32) -> bf16 plane, once per call ----
__global__ __launch_bounds__(256) void xbf_kernel(const float* __restrict__ x,
                                                  ushortT* __restrict__ xb) {
    int i = blockIdx.x * 256 + threadIdx.x;  // 8-elem group; grid exact (6250)
    float4v a = ((const float4v*)x)[2 * i];
    float4v b = ((const float4v*)x)[2 * i + 1];
    ushortT o[8];
#pragma unroll
    for (int j = 0; j < 4; j++) o[j] = f2bf(a[j]);
#pragma unroll
    for (int j = 0; j < 4; j++) o[4 + j] = f2bf(b[j]);
    ((uint4v*)xb)[i] = *(const uint4v*)o;
}

// ---- CSR build ----
__global__ __launch_bounds__(256) void hist_kernel(const int* __restrict__ dst,
                                                   int* __restrict__ counts) {
    int e = blockIdx.x * 256 + threadIdx.x;
    if (e < N_EDGES) atomicAdd(&counts[dst[e]], 1);
}

#define SCAN_BLOCKS 98  // 98*1024 >= 100000

__global__ __launch_bounds__(1024) void blockscan_kernel(const int* __restrict__ counts,
                                                         int* __restrict__ local,
                                                         int* __restrict__ bsums) {
    __shared__ int wsum[16];
    int tid = threadIdx.x, lane = tid & 63, wid = tid >> 6;
    int i = blockIdx.x * 1024 + tid;
    int v = (i < N_NODES) ? counts[i] : 0;
    int incl = v;
#pragma unroll
    for (int off = 1; off < 64; off <<= 1) {
        int u = __shfl_up(incl, off);
        if (lane >= off) incl += u;
    }
    if (lane == 63) wsum[wid] = incl;
    __syncthreads();
    if (wid == 0) {
        int s = (lane < 16) ? wsum[lane] : 0;
#pragma unroll
        for (int off = 1; off < 16; off <<= 1) {
            int u = __shfl_up(s, off);
            if (lane >= off) s += u;
        }
        if (lane < 16) wsum[lane] = s;
    }
    __syncthreads();
    int excl = ((wid == 0) ? 0 : wsum[wid - 1]) + incl - v;
    if (i < N_NODES) local[i] = excl;
    if (tid == 0) bsums[blockIdx.x] = wsum[15];
}

__global__ __launch_bounds__(1024) void fixup_kernel(const int* __restrict__ local,
                                                     const int* __restrict__ bsums,
                                                     int* __restrict__ offsets,
                                                     int* __restrict__ cursor) {
    __shared__ int sbase;
    int tid = threadIdx.x;
    if (tid < 64) {
        int s = 0;
        for (int j = tid; j < blockIdx.x; j += 64) s += bsums[j];
#pragma unroll
        for (int off = 32; off >= 1; off >>= 1) s += __shfl_xor(s, off);
        if (tid == 0) sbase = s;
    }
    __syncthreads();
    int base = sbase;
    int i = blockIdx.x * 1024 + tid;
    if (i < N_NODES) {
        int o = local[i] + base;
        offsets[i] = o;
        cursor[i] = o;
    }
    if (blockIdx.x == 0 && tid == 0) offsets[N_NODES] = N_EDGES;
}

__global__ __launch_bounds__(256) void fill_kernel(const int* __restrict__ src,
                                                   const int* __restrict__ dst,
                                                   int* __restrict__ cursor,
                                                   int* __restrict__ eidx) {
    int e = blockIdx.x * 256 + threadIdx.x;
    if (e < N_EDGES) {
        int pos = atomicAdd(&cursor[dst[e]], 1);
        eidx[pos] = src[e];
    }
}

// lgkm-only wait: vmcnt=63, expcnt=7, lgkmcnt=0 (gfx9 encoding)
#define LGKM0() __builtin_amdgcn_s_waitcnt(0xC07F)

// ---- fused GIN layer: out = act(relu((h + sum_nbr h) @ W1 + b1) @ W2 + b2) ----
// 512 threads (8 waves), one 32-row unit per wave, grid 391 (3128 waves; all
// units resident in ONE round). LDS 80KB = W image 64KB + 8 x 1KB per-wave
// 16-row transpose scratch => 2 blocks/CU = 16 waves/CU = 4 waves/SIMD
// (double round-4's latency hiding; gather was parallelism-bound).
// __launch_bounds__(512,4) pins VGPR<=128 so the occupancy holds.
// Aggregation fused into the A-fragment build (bit-identical to agg_kernel order);
// transpose via 16-row halves (round-2-proven); W2 restaged over dead W1 region.
// OUT 1: bf16 plane (stride 128) + relu.  OUT 2: f32 (stride 128), no relu.
template <int OUT>
__global__ __launch_bounds__(512, 4) void fused_kernel(const ushortT* __restrict__ Hprev,
                                                       const int* __restrict__ offs,
                                                       const int* __restrict__ eidx,
                                                       const ushortT* __restrict__ w1HL,
                                                       const ushortT* __restrict__ w2HL,
                                                       const float* __restrict__ b1,
                                                       const float* __restrict__ b2,
                                                       void* __restrict__ out) {
    __shared__ ushortT SH[40960];  // 80KB: W image [0,32768), scratch [32768,40960)

    int t = threadIdx.x, lane = t & 63, wid = t >> 6;  // wid 0..7
    int unit = blockIdx.x * 8 + wid;  // 32-row unit; 3125 total
    int quad = lane >> 4, col16 = lane & 15;
    bool active = unit < (N_NODES / 32);
    int row0 = unit * 32;

    float bia1[8], bia2[8];
#pragma unroll
    for (int n = 0; n < 8; n++) {
        bia1[n] = b1[n * 16 + col16];
        bia2[n] = b2[n * 16 + col16];
    }

    // stage W1 images: coalesced b128, 512 threads x 8 iters
#pragma unroll
    for (int i = 0; i < 8; i++) {
        int idx = (t + i * 512) * 8;
        *(uint4v*)&SH[idx] = *(const uint4v*)&w1HL[idx];
    }
    __syncthreads();

    // ---- fused aggregation -> A fragments (ah/al) ----
    short8 ah[4][2], al[4][2];
    if (active) {
#pragma unroll
        for (int r = 0; r < 2; r++) {
            int v = row0 + r * 16 + col16;
            int beg = offs[v], end = offs[v + 1];
            int cnt = end - beg;
            const ushortT* hq = Hprev + (size_t)v * DIM + quad * 8;
            float accf[4][8];
#pragma unroll
            for (int s = 0; s < 4; s++) {  // self term first (same order as agg_kernel)
                short8 x = *(const short8*)(hq + s * 32);
                uint4v u = __builtin_bit_cast(uint4v, x);
#pragma unroll
                for (int p = 0; p < 4; p++) {
                    accf[s][2 * p]     = bflo(u[p]);
                    accf[s][2 * p + 1] = bfhi(u[p]);
                }
            }
            for (int base = 0; base < cnt; base += 4) {
                int idx[4];
#pragma unroll
                for (int jj = 0; jj < 4; jj++) {
                    int q = base + jj;
                    if (q > cnt - 1) q = cnt - 1;  // clamp: dup loads hit L1
                    idx[jj] = eidx[beg + q];
                }
                short8 vv[4][4];
#pragma unroll
                for (int jj = 0; jj < 4; jj++) {
                    const ushortT* hu = Hprev + (size_t)idx[jj] * DIM + quad * 8;
#pragma unroll
                    for (int s = 0; s < 4; s++) vv[jj][s] = *(const short8*)(hu + s * 32);
                }
                int rem = cnt - base;  // per-lane predicate
#pragma unroll
                for (int jj = 0; jj < 4; jj++)
                    if (jj < rem) {
#pragma unroll
                        for (int s = 0; s < 4; s++) {
                            uint4v u = __builtin_bit_cast(uint4v, vv[jj][s]);
#pragma unroll
                            for (int p = 0; p < 4; p++) {
                                accf[s][2 * p]     += bflo(u[p]);
                                accf[s][2 * p + 1] += bfhi(u[p]);
                            }
                        }
                    }
            }
            // RNE hi/lo split -> MFMA A fragments (identical to old z hi/lo planes)
#pragma unroll
            for (int s = 0; s < 4; s++) {
                ushortT oh[8], ol[8];
#pragma unroll
                for (int e = 0; e < 8; e++) {
                    ushortT hi = f2bf(accf[s][e]);
                    oh[e] = hi;
                    ol[e] = f2bf(accf[s][e] - bf2f(hi));
                }
                ah[s][r] = *(const short8*)oh;
                al[s][r] = *(const short8*)ol;
            }
        }
    }

    // ---- GEMM1: acc = z @ W1 (3-term bf16 split) ----
    float4v acc[2][8];
    if (active) {
#pragma unroll
        for (int r = 0; r < 2; r++)
#pragma unroll
            for (int n = 0; n < 8; n++) acc[r][n] = (float4v)0.0f;
#pragma unroll
        for (int s = 0; s < 4; s++) {
            short8 bh[8], bl[8];
#pragma unroll
            for (int n = 0; n < 8; n++) {
                int addr = (n * 16 + col16) * 128 + (((s * 4 + quad) ^ col16) << 3);
                bh[n] = *(const short8*)&SH[addr];
                bl[n] = *(const short8*)&SH[16384 + addr];
            }
            __builtin_amdgcn_s_setprio(1);
#pragma unroll
            for (int r = 0; r < 2; r++)
#pragma unroll
                for (int n = 0; n < 8; n++) {
                    acc[r][n] = __builtin_amdgcn_mfma_f32_16x16x32_bf16(ah[s][r], bh[n], acc[r][n], 0, 0, 0);
                    acc[r][n] = __builtin_amdgcn_mfma_f32_16x16x32_bf16(al[s][r], bh[n], acc[r][n], 0, 0, 0);
                    acc[r][n] = __builtin_amdgcn_mfma_f32_16x16x32_bf16(ah[s][r], bl[n], acc[r][n], 0, 0, 0);
                }
            __builtin_amdgcn_s_setprio(0);
        }
    }
    __syncthreads();  // all waves done reading W1

    // restage W2 over the dead W1 region (L2-hit, 64KB/block)
#pragma unroll
    for (int i = 0; i < 8; i++) {
        int idx = (t + i * 512) * 8;
        *(uint4v*)&SH[idx] = *(const uint4v*)&w2HL[idx];
    }
    __syncthreads();

    float4v acc2[2][8];
    if (active) {
#pragma unroll
        for (int r = 0; r < 2; r++)
#pragma unroll
            for (int n = 0; n < 8; n++) acc2[r][n] = (float4v)0.0f;
        ushortT* scr = &SH[32768 + wid * 1024];  // 16 rows x 64 ushorts, XOR-swizzled
#pragma unroll
        for (int s2 = 0; s2 < 4; s2++) {
            short8 a2h[2], a2l[2];
#pragma unroll
            for (int r = 0; r < 2; r++) {
                LGKM0();  // WAR: prior scratch reads landed before overwrite
#pragma unroll
                for (int h = 0; h < 2; h++) {
                    int n = s2 * 2 + h;
#pragma unroll
                    for (int i = 0; i < 4; i++) {
                        float v = acc[r][n][i] + bia1[n];
                        v = v > 0.0f ? v : 0.0f;
                        int row = quad * 4 + i;  // local row in this 16-row half
                        ushortT hi = f2bf(v);
                        ushortT lo = f2bf(v - bf2f(hi));
                        int c8 = h * 2 + (col16 >> 3);
                        int base = row * 64 + (col16 & 7);
                        scr[base + ((c8 ^ (row & 7)) << 3)]       = hi;
                        scr[base + (((4 + c8) ^ (row & 7)) << 3)] = lo;
                    }
                }
                LGKM0();  // writes visible before readback (per-wave scratch)
                int rrow = col16;
                a2h[r] = *(const short8*)&scr[rrow * 64 + ((quad ^ (rrow & 7)) << 3)];
                a2l[r] = *(const short8*)&scr[rrow * 64 + (((4 + quad) ^ (rrow & 7)) << 3)];
            }
            short8 bh[8], bl[8];
#pragma unroll
            for (int n = 0; n < 8; n++) {
                int addr = (n * 16 + col16) * 128 + (((s2 * 4 + quad) ^ col16) << 3);
                bh[n] = *(const short8*)&SH[addr];
                bl[n] = *(const short8*)&SH[16384 + addr];
            }
            __builtin_amdgcn_s_setprio(1);
#pragma unroll
            for (int r = 0; r < 2; r++)
#pragma unroll
                for (int n = 0; n < 8; n++) {
                    acc2[r][n] = __builtin_amdgcn_mfma_f32_16x16x32_bf16(a2h[r], bh[n], acc2[r][n], 0, 0, 0);
                    acc2[r][n] = __builtin_amdgcn_mfma_f32_16x16x32_bf16(a2l[r], bh[n], acc2[r][n], 0, 0, 0);
                    acc2[r][n] = __builtin_amdgcn_mfma_f32_16x16x32_bf16(a2h[r], bl[n], acc2[r][n], 0, 0, 0);
                }
            __builtin_amdgcn_s_setprio(0);
        }
    }
    __syncthreads();  // W region dead after all waves' K-loops
    if (!active) return;

    // epilogue: C/D layout col=lane&15 (within n-block), row=quad*4+i.
    // Two 16-row passes through per-wave LDS scratch -> coalesced stores.
#pragma unroll
    for (int r = 0; r < 2; r++) {
        if constexpr (OUT == 1) {
            ushortT* tr = &SH[wid * 2304];  // 8 x 2304 = 18432 <= 40960
#pragma unroll
            for (int n = 0; n < 8; n++)
#pragma unroll
                for (int i = 0; i < 4; i++) {
                    float v = acc2[r][n][i] + bia2[n];
                    v = v > 0.0f ? v : 0.0f;
                    tr[(quad * 4 + i) * 136 + n * 16 + col16] = f2bf(v);
                }
            LGKM0();
#pragma unroll
            for (int p = 0; p < 4; p++) {
                int row = p * 4 + (lane >> 4);
                int seg = lane & 15;
                uint4v val = *(const uint4v*)&tr[row * 136 + seg * 8];
                *(uint4v*)((ushortT*)out + (size_t)(row0 + r * 16 + row) * 128 + seg * 8) = val;
            }
        } else {
            float* trf = (float*)&SH[wid * 4352];  // stride 132 floats; 8x4352x2B=69632 <= 81920
#pragma unroll
            for (int n = 0; n < 8; n++)
#pragma unroll
                for (int i = 0; i < 4; i++)
                    trf[(quad * 4 + i) * 132 + n * 16 + col16] = acc2[r][n][i] + bia2[n];
            LGKM0();
#pragma unroll
            for (int p = 0; p < 8; p++) {
                int row = p * 2 + (lane >> 5);
                int seg = lane & 31;
                float4v val = *(const float4v*)&trf[row * 132 + seg * 4];
                *(float4v*)((float*)out + (size_t)(row0 + r * 16 + row) * 128 + seg * 4) = val;
            }
        }
        if (r == 0) LGKM0();  // WAR guard before pass 2 overwrite
    }
}

extern "C" void kernel_launch(void* const* d_in, const int* in_sizes, int n_in,
                              void* d_out, int out_size, void* d_ws, size_t ws_size,
                              hipStream_t stream) {
    const float* x  = (const float*)d_in[0];
    const int* src  = (const int*)d_in[1];
    const int* dst  = (const int*)d_in[2];
    const float* W1 = (const float*)d_in[3];
    const float* b1 = (const float*)d_in[4];
    const float* W2 = (const float*)d_in[5];
    const float* b2 = (const float*)d_in[6];

    char* ws = (char*)d_ws;
    ushortT* wt     = (ushortT*)ws;                        // 128 KB: W1H|W1L|W2H|W2L (swizzled)
    int*     offs   = (int*)(ws + 131072);                 // 100001 ints
    int*     cursor = (int*)(ws + 531456);                 // 100000 ints
    int*     eidx   = (int*)(ws + 931456);                 // 600000 ints
    int*     local  = (int*)(ws + 3331456);                // 100000 ints
    int*     bsums  = (int*)(ws + 3731456);                // 98 ints
    ushortT* xbf    = (ushortT*)(ws + 3731968);            // 25.6 MB bf16 x
    ushortT* h1     = (ushortT*)(ws + 3731968 + 25600000); // 25.6 MB bf16 h (layer0 out)
    ushortT* h2     = (ushortT*)(ws + 3731968 + 51200000); // 25.6 MB bf16 h (layer1 out)
    // total ~80.5 MB

    const ushortT* w1 = wt;          // WH at +0, WL at +16384
    const ushortT* w2 = wt + 32768;  // WH at +0, WL at +16384

    dim3 blk(256);
    const int gEdge = (N_EDGES + 255) / 256;    // 2344
    const int gFus  = (N_NODES / 32 + 7) / 8;   // 391 (3125 32-row units, 8 waves/block)
    const int gXbf  = N_NODES * DIM / 8 / 256;  // 6250 exact

    prep_kernel<<<2, blk, 0, stream>>>(W1, W2, wt);
    xbf_kernel<<<gXbf, blk, 0, stream>>>(x, xbf);
    hipMemsetAsync(cursor, 0, N_NODES * sizeof(int), stream);
    hist_kernel<<<gEdge, blk, 0, stream>>>(dst, cursor);
    blockscan_kernel<<<SCAN_BLOCKS, 1024, 0, stream>>>(cursor, local, bsums);
    fixup_kernel<<<SCAN_BLOCKS, 1024, 0, stream>>>(local, bsums, offs, cursor);
    fill_kernel<<<gEdge, blk, 0, stream>>>(src, dst, cursor, eidx);

    // layer 0: gather from xbf, write h1
    fused_kernel<1><<<gFus, 512, 0, stream>>>(xbf, offs, eidx, w1, w2, b1, b2, h1);
    // layer 1: gather from h1, write h2 (ping-pong: no gather/write race)
    fused_kernel<1><<<gFus, 512, 0, stream>>>(h1, offs, eidx, w1, w2, b1, b2, h2);
    // layer 2: gather from h2, write f32 d_out (no relu)
    fused_kernel<2><<<gFus, 512, 0, stream>>>(h2, offs, eidx, w1, w2, b1, b2, (float*)d_out);
}

// Round 7
// 590.725 us; speedup vs baseline: 1.1126x; 1.1126x over previous
//
#include <hip/hip_runtime.h>

#define N_NODES 100000
#define N_EDGES 600000
#define DIM 128
#define N_UNITS (N_NODES / 32)  // 3125

typedef unsigned short ushortT;
typedef __attribute__((ext_vector_type(8))) short short8;
typedef __attribute__((ext_vector_type(4))) float float4v;
typedef __attribute__((ext_vector_type(4))) unsigned int uint4v;

__device__ __forceinline__ float bf2f(ushortT h) {
    return __builtin_bit_cast(float, ((unsigned int)h) << 16);
}
__device__ __forceinline__ float bflo(unsigned int p) {
    return __builtin_bit_cast(float, p << 16);
}
__device__ __forceinline__ float bfhi(unsigned int p) {
    return __builtin_bit_cast(float, p & 0xffff0000u);
}
__device__ __forceinline__ ushortT f2bf(float f) {  // RNE
    unsigned int x = __builtin_bit_cast(unsigned int, f);
    unsigned int r = (x + 0x7fffu + ((x >> 16) & 1u)) >> 16;
    return (ushortT)r;
}

// ---- prep: W (128x128 f32, KxN) -> transposed + XOR-swizzled bf16 hi/lo images
// element (k,n) stored at  n*128 + (((k>>3) ^ (n&15))<<3) + (k&7)
__global__ __launch_bounds__(256) void prep_kernel(const float* __restrict__ W1,
                                                   const float* __restrict__ W2,
                                                   ushortT* __restrict__ wt) {
    const float* Wf = (blockIdx.x == 0) ? W1 : W2;
    ushortT* outh = wt + blockIdx.x * 32768;
    ushortT* outl = outh + 16384;
    int t = threadIdx.x;
#pragma unroll
    for (int i = 0; i < 16; i++) {
        int c = t + i * 256;            // 0..4095
        int k = c >> 5;
        int n0 = (c & 31) * 4;
        float4v w = *(const float4v*)(Wf + k * 128 + n0);
        int g = k >> 3, kk = k & 7;
#pragma unroll
        for (int j = 0; j < 4; j++) {
            int n = n0 + j;
            ushortT wh = f2bf(w[j]);
            ushortT wl = f2bf(w[j] - bf2f(wh));
            int addr = n * 128 + ((g ^ (n & 15)) << 3) + kk;
            outh[addr] = wh;
            outl[addr] = wl;
        }
    }
}

// ---- x (f32) -> bf16 plane, once per call ----
__global__ __launch_bounds__(256) void xbf_kernel(const float* __restrict__ x,
                                                  ushortT* __restrict__ xb) {
    int i = blockIdx.x * 256 + threadIdx.x;  // 8-elem group; grid exact (6250)
    float4v a = ((const float4v*)x)[2 * i];
    float4v b = ((const float4v*)x)[2 * i + 1];
    ushortT o[8];
#pragma unroll
    for (int j = 0; j < 4; j++) o[j] = f2bf(a[j]);
#pragma unroll
    for (int j = 0; j < 4; j++) o[4 + j] = f2bf(b[j]);
    ((uint4v*)xb)[i] = *(const uint4v*)o;
}

// ---- CSR build ----
__global__ __launch_bounds__(256) void hist_kernel(const int* __restrict__ dst,
                                                   int* __restrict__ counts) {
    int e = blockIdx.x * 256 + threadIdx.x;
    if (e < N_EDGES) atomicAdd(&counts[dst[e]], 1);
}

#define SCAN_BLOCKS 98  // 98*1024 >= 100000

__global__ __launch_bounds__(1024) void blockscan_kernel(const int* __restrict__ counts,
                                                         int* __restrict__ local,
                                                         int* __restrict__ bsums) {
    __shared__ int wsum[16];
    int tid = threadIdx.x, lane = tid & 63, wid = tid >> 6;
    int i = blockIdx.x * 1024 + tid;
    int v = (i < N_NODES) ? counts[i] : 0;
    int incl = v;
#pragma unroll
    for (int off = 1; off < 64; off <<= 1) {
        int u = __shfl_up(incl, off);
        if (lane >= off) incl += u;
    }
    if (lane == 63) wsum[wid] = incl;
    __syncthreads();
    if (wid == 0) {
        int s = (lane < 16) ? wsum[lane] : 0;
#pragma unroll
        for (int off = 1; off < 16; off <<= 1) {
            int u = __shfl_up(s, off);
            if (lane >= off) s += u;
        }
        if (lane < 16) wsum[lane] = s;
    }
    __syncthreads();
    int excl = ((wid == 0) ? 0 : wsum[wid - 1]) + incl - v;
    if (i < N_NODES) local[i] = excl;
    if (tid == 0) bsums[blockIdx.x] = wsum[15];
}

__global__ __launch_bounds__(1024) void fixup_kernel(const int* __restrict__ local,
                                                     const int* __restrict__ bsums,
                                                     int* __restrict__ offsets,
                                                     int* __restrict__ cursor) {
    __shared__ int sbase;
    int tid = threadIdx.x;
    if (tid < 64) {
        int s = 0;
        for (int j = tid; j < blockIdx.x; j += 64) s += bsums[j];
#pragma unroll
        for (int off = 32; off >= 1; off >>= 1) s += __shfl_xor(s, off);
        if (tid == 0) sbase = s;
    }
    __syncthreads();
    int base = sbase;
    int i = blockIdx.x * 1024 + tid;
    if (i < N_NODES) {
        int o = local[i] + base;
        offsets[i] = o;
        cursor[i] = o;
    }
    if (blockIdx.x == 0 && tid == 0) offsets[N_NODES] = N_EDGES;
}

__global__ __launch_bounds__(256) void fill_kernel(const int* __restrict__ src,
                                                   const int* __restrict__ dst,
                                                   int* __restrict__ cursor,
                                                   int* __restrict__ eidx) {
    int e = blockIdx.x * 256 + threadIdx.x;
    if (e < N_EDGES) {
        int pos = atomicAdd(&cursor[dst[e]], 1);
        eidx[pos] = src[e];
    }
}

// lgkm-only wait: vmcnt=63, expcnt=7, lgkmcnt=0 (gfx9 encoding)
#define LGKM0() __builtin_amdgcn_s_waitcnt(0xC07F)

// ---- fused GIN layer: out = act(relu((h + sum_nbr h) @ W1 + b1) @ W2 + b2) ----
// Barrier-free persistent structure: 512 threads (8 waves), grid 256 (1 block/CU,
// LDS 144KB => 2 waves/SIMD). W1H|W1L|W2H|W2L all staged once (128KB), single
// __syncthreads; then waves independently pop 32-row units off a global atomic
// counter (perfect balance, no straggler barriers, natural phase desync).
// Gather pipelined: double-buffered neighbor rows (vA/vB) + eidx prefetched 2
// batches ahead -> ~32 loads continuously in flight (round 4 was ~16 at 50% duty,
// Little's-law bound at 1.77 TB/s). Accumulation order identical to the original
// agg_kernel (self, then edges ascending) => numerics bit-identical.
// Epilogue: 4-row passes through the 2KB/wave scratch, 256B-coalesced stores.
// OUT 1: bf16 plane (stride 128) + relu.  OUT 2: f32 (stride 128), no relu.
template <int OUT>
__global__ __launch_bounds__(512, 2) void fused_kernel(const ushortT* __restrict__ Hprev,
                                                       const int* __restrict__ offs,
                                                       const int* __restrict__ eidx,
                                                       const ushortT* __restrict__ wtAll,
                                                       const float* __restrict__ b1,
                                                       const float* __restrict__ b2,
                                                       void* __restrict__ out,
                                                       int* __restrict__ ctr) {
    __shared__ ushortT SH[73728];  // 144KB: W1H|W1L|W2H|W2L [0,65536), scratch [65536,73728)

    int t = threadIdx.x, lane = t & 63, wid = t >> 6;  // wid 0..7
    int quad = lane >> 4, col16 = lane & 15;

    float bia1[8], bia2[8];
#pragma unroll
    for (int n = 0; n < 8; n++) {
        bia1[n] = b1[n * 16 + col16];
        bia2[n] = b2[n * 16 + col16];
    }

    // stage all four W images (128KB), once
#pragma unroll
    for (int i = 0; i < 16; i++) {
        int idx = (t + i * 512) * 8;
        *(uint4v*)&SH[idx] = *(const uint4v*)&wtAll[idx];
    }
    __syncthreads();  // the only block-wide barrier

    ushortT* scr = &SH[65536 + wid * 1024];  // 2KB per-wave scratch

    for (;;) {
        int u = 0;
        if (lane == 0) u = atomicAdd(ctr, 1);
        u = __builtin_amdgcn_readfirstlane(u);
        if (u >= N_UNITS) break;
        int row0 = u * 32;

        // ---- pipelined fused aggregation -> A fragments (ah/al) ----
        short8 ah[4][2], al[4][2];
#pragma unroll
        for (int r = 0; r < 2; r++) {
            int v = row0 + r * 16 + col16;
            const ushortT* hq = Hprev + (size_t)v * DIM + quad * 8;
            // self rows: issue immediately (independent of offs/eidx chain)
            short8 sf[4];
#pragma unroll
            for (int s = 0; s < 4; s++) sf[s] = *(const short8*)(hq + s * 32);
            int beg = offs[v];
            int cnt = offs[v + 1] - beg;
            int nb = (cnt + 3) >> 2;  // per-lane batch count
            int iA[4], iB[4];
            if (nb > 0) {
#pragma unroll
                for (int jj = 0; jj < 4; jj++) {
                    int q = jj; if (q > cnt - 1) q = cnt - 1;
                    iA[jj] = eidx[beg + q];
                }
            }
            if (nb > 1) {
#pragma unroll
                for (int jj = 0; jj < 4; jj++) {
                    int q = 4 + jj; if (q > cnt - 1) q = cnt - 1;
                    iB[jj] = eidx[beg + q];
                }
            }
            // init accf from self (overlaps eidx latency)
            float accf[4][8];
#pragma unroll
            for (int s = 0; s < 4; s++) {
                uint4v uu = __builtin_bit_cast(uint4v, sf[s]);
#pragma unroll
                for (int p = 0; p < 4; p++) {
                    accf[s][2 * p]     = bflo(uu[p]);
                    accf[s][2 * p + 1] = bfhi(uu[p]);
                }
            }
            short8 vA[4][4], vB[4][4];
            if (nb > 0) {
#pragma unroll
                for (int jj = 0; jj < 4; jj++) {
                    const ushortT* hu = Hprev + (size_t)iA[jj] * DIM + quad * 8;
#pragma unroll
                    for (int s = 0; s < 4; s++) vA[jj][s] = *(const short8*)(hu + s * 32);
                }
            }
            int b = 0;
            while (b < nb) {
                // even step: consume vA, prefetch idx b+2 -> iA, rows b+1 -> vB
                if (b + 2 < nb) {
#pragma unroll
                    for (int jj = 0; jj < 4; jj++) {
                        int q = (b + 2) * 4 + jj; if (q > cnt - 1) q = cnt - 1;
                        iA[jj] = eidx[beg + q];
                    }
                }
                if (b + 1 < nb) {
#pragma unroll
                    for (int jj = 0; jj < 4; jj++) {
                        const ushortT* hu = Hprev + (size_t)iB[jj] * DIM + quad * 8;
#pragma unroll
                        for (int s = 0; s < 4; s++) vB[jj][s] = *(const short8*)(hu + s * 32);
                    }
                }
                {
                    int rem = cnt - b * 4;
#pragma unroll
                    for (int jj = 0; jj < 4; jj++)
                        if (jj < rem) {
#pragma unroll
                            for (int s = 0; s < 4; s++) {
                                uint4v uu = __builtin_bit_cast(uint4v, vA[jj][s]);
#pragma unroll
                                for (int p = 0; p < 4; p++) {
                                    accf[s][2 * p]     += bflo(uu[p]);
                                    accf[s][2 * p + 1] += bfhi(uu[p]);
                                }
                            }
                        }
                }
                b++;
                if (b >= nb) break;
                // odd step: consume vB, prefetch idx b+2 -> iB, rows b+1 -> vA
                if (b + 2 < nb) {
#pragma unroll
                    for (int jj = 0; jj < 4; jj++) {
                        int q = (b + 2) * 4 + jj; if (q > cnt - 1) q = cnt - 1;
                        iB[jj] = eidx[beg + q];
                    }
                }
                if (b + 1 < nb) {
#pragma unroll
                    for (int jj = 0; jj < 4; jj++) {
                        const ushortT* hu = Hprev + (size_t)iA[jj] * DIM + quad * 8;
#pragma unroll
                        for (int s = 0; s < 4; s++) vA[jj][s] = *(const short8*)(hu + s * 32);
                    }
                }
                {
                    int rem = cnt - b * 4;
#pragma unroll
                    for (int jj = 0; jj < 4; jj++)
                        if (jj < rem) {
#pragma unroll
                            for (int s = 0; s < 4; s++) {
                                uint4v uu = __builtin_bit_cast(uint4v, vB[jj][s]);
#pragma unroll
                                for (int p = 0; p < 4; p++) {
                                    accf[s][2 * p]     += bflo(uu[p]);
                                    accf[s][2 * p + 1] += bfhi(uu[p]);
                                }
                            }
                        }
                }
                b++;
            }
            // RNE hi/lo split -> MFMA A fragments
#pragma unroll
            for (int s = 0; s < 4; s++) {
                ushortT oh[8], ol[8];
#pragma unroll
                for (int e = 0; e < 8; e++) {
                    ushortT hi = f2bf(accf[s][e]);
                    oh[e] = hi;
                    ol[e] = f2bf(accf[s][e] - bf2f(hi));
                }
                ah[s][r] = *(const short8*)oh;
                al[s][r] = *(const short8*)ol;
            }
        }

        // ---- GEMM1: acc = z @ W1 (3-term bf16 split) ----
        float4v acc[2][8];
#pragma unroll
        for (int r = 0; r < 2; r++)
#pragma unroll
            for (int n = 0; n < 8; n++) acc[r][n] = (float4v)0.0f;
#pragma unroll
        for (int s = 0; s < 4; s++) {
            short8 bh[8], bl[8];
#pragma unroll
            for (int n = 0; n < 8; n++) {
                int addr = (n * 16 + col16) * 128 + (((s * 4 + quad) ^ col16) << 3);
                bh[n] = *(const short8*)&SH[addr];
                bl[n] = *(const short8*)&SH[16384 + addr];
            }
            __builtin_amdgcn_s_setprio(1);
#pragma unroll
            for (int r = 0; r < 2; r++)
#pragma unroll
                for (int n = 0; n < 8; n++) {
                    acc[r][n] = __builtin_amdgcn_mfma_f32_16x16x32_bf16(ah[s][r], bh[n], acc[r][n], 0, 0, 0);
                    acc[r][n] = __builtin_amdgcn_mfma_f32_16x16x32_bf16(al[s][r], bh[n], acc[r][n], 0, 0, 0);
                    acc[r][n] = __builtin_amdgcn_mfma_f32_16x16x32_bf16(ah[s][r], bl[n], acc[r][n], 0, 0, 0);
                }
            __builtin_amdgcn_s_setprio(0);
        }

        // ---- transpose (per-wave scratch, 16-row halves) + GEMM2 ----
        float4v acc2[2][8];
#pragma unroll
        for (int r = 0; r < 2; r++)
#pragma unroll
            for (int n = 0; n < 8; n++) acc2[r][n] = (float4v)0.0f;
#pragma unroll
        for (int s2 = 0; s2 < 4; s2++) {
            short8 a2h[2], a2l[2];
#pragma unroll
            for (int r = 0; r < 2; r++) {
                LGKM0();  // WAR: prior scratch reads landed before overwrite
#pragma unroll
                for (int h = 0; h < 2; h++) {
                    int n = s2 * 2 + h;
#pragma unroll
                    for (int i = 0; i < 4; i++) {
                        float v = acc[r][n][i] + bia1[n];
                        v = v > 0.0f ? v : 0.0f;
                        int row = quad * 4 + i;  // local row in this 16-row half
                        ushortT hi = f2bf(v);
                        ushortT lo = f2bf(v - bf2f(hi));
                        int c8 = h * 2 + (col16 >> 3);
                        int base = row * 64 + (col16 & 7);
                        scr[base + ((c8 ^ (row & 7)) << 3)]       = hi;
                        scr[base + (((4 + c8) ^ (row & 7)) << 3)] = lo;
                    }
                }
                LGKM0();  // writes visible before readback (per-wave scratch)
                int rrow = col16;
                a2h[r] = *(const short8*)&scr[rrow * 64 + ((quad ^ (rrow & 7)) << 3)];
                a2l[r] = *(const short8*)&scr[rrow * 64 + (((4 + quad) ^ (rrow & 7)) << 3)];
            }
            short8 bh[8], bl[8];
#pragma unroll
            for (int n = 0; n < 8; n++) {
                int addr = (n * 16 + col16) * 128 + (((s2 * 4 + quad) ^ col16) << 3);
                bh[n] = *(const short8*)&SH[32768 + addr];
                bl[n] = *(const short8*)&SH[49152 + addr];
            }
            __builtin_amdgcn_s_setprio(1);
#pragma unroll
            for (int r = 0; r < 2; r++)
#pragma unroll
                for (int n = 0; n < 8; n++) {
                    acc2[r][n] = __builtin_amdgcn_mfma_f32_16x16x32_bf16(a2h[r], bh[n], acc2[r][n], 0, 0, 0);
                    acc2[r][n] = __builtin_amdgcn_mfma_f32_16x16x32_bf16(a2l[r], bh[n], acc2[r][n], 0, 0, 0);
                    acc2[r][n] = __builtin_amdgcn_mfma_f32_16x16x32_bf16(a2h[r], bl[n], acc2[r][n], 0, 0, 0);
                }
            __builtin_amdgcn_s_setprio(0);
        }

        // ---- epilogue: 4-row passes through the 2KB scratch, coalesced stores ----
        // C/D layout: col = n*16+col16, row = r*16 + quad*4 + i
        LGKM0();  // GEMM2's last scratch reads done before epilogue overwrites
#pragma unroll
        for (int r = 0; r < 2; r++) {
            if constexpr (OUT == 1) {
#pragma unroll
                for (int i = 0; i < 4; i++) {
#pragma unroll
                    for (int n = 0; n < 8; n++) {
                        float v = acc2[r][n][i] + bia2[n];
                        v = v > 0.0f ? v : 0.0f;
                        scr[quad * 136 + n * 16 + col16] = f2bf(v);
                    }
                    LGKM0();
                    uint4v val = *(const uint4v*)&scr[(lane >> 4) * 136 + (lane & 15) * 8];
                    *(uint4v*)((ushortT*)out +
                               (size_t)(row0 + r * 16 + (lane >> 4) * 4 + i) * 128 + (lane & 15) * 8) = val;
                    LGKM0();  // WAR before next pass overwrites scratch
                }
            } else {
                float* trf = (float*)scr;  // 4 rows x 68 floats = 1088B <= 2KB
#pragma unroll
                for (int i = 0; i < 4; i++)
#pragma unroll
                    for (int nh = 0; nh < 2; nh++) {
#pragma unroll
                        for (int k = 0; k < 4; k++) {
                            int n = nh * 4 + k;
                            trf[quad * 68 + k * 16 + col16] = acc2[r][n][i] + bia2[n];
                        }
                        LGKM0();
                        float4v val = *(const float4v*)&trf[(lane >> 4) * 68 + (lane & 15) * 4];
                        *(float4v*)((float*)out +
                                    (size_t)(row0 + r * 16 + (lane >> 4) * 4 + i) * 128 +
                                    nh * 64 + (lane & 15) * 4) = val;
                        LGKM0();
                    }
            }
        }
    }
}

extern "C" void kernel_launch(void* const* d_in, const int* in_sizes, int n_in,
                              void* d_out, int out_size, void* d_ws, size_t ws_size,
                              hipStream_t stream) {
    const float* x  = (const float*)d_in[0];
    const int* src  = (const int*)d_in[1];
    const int* dst  = (const int*)d_in[2];
    const float* W1 = (const float*)d_in[3];
    const float* b1 = (const float*)d_in[4];
    const float* W2 = (const float*)d_in[5];
    const float* b2 = (const float*)d_in[6];

    char* ws = (char*)d_ws;
    ushortT* wt     = (ushortT*)ws;                        // 128 KB: W1H|W1L|W2H|W2L (swizzled)
    int*     offs   = (int*)(ws + 131072);                 // 100001 ints
    int*     cursor = (int*)(ws + 531456);                 // 100000 ints
    int*     eidx   = (int*)(ws + 931456);                 // 600000 ints
    int*     local  = (int*)(ws + 3331456);                // 100000 ints
    int*     bsums  = (int*)(ws + 3731456);                // 98 ints (ends 3731848)
    int*     ctrs   = (int*)(ws + 3731848);                // 3 ints (unit pop counters)
    ushortT* xbf    = (ushortT*)(ws + 3731968);            // 25.6 MB bf16 x
    ushortT* h1     = (ushortT*)(ws + 3731968 + 25600000); // 25.6 MB bf16 h (layer0 out)
    ushortT* h2     = (ushortT*)(ws + 3731968 + 51200000); // 25.6 MB bf16 h (layer1 out)
    // total ~80.5 MB

    dim3 blk(256);
    const int gEdge = (N_EDGES + 255) / 256;    // 2344
    const int gXbf  = N_NODES * DIM / 8 / 256;  // 6250 exact
    const int gFus  = 256;                      // persistent: 1 block/CU, 8 waves

    prep_kernel<<<2, blk, 0, stream>>>(W1, W2, wt);
    xbf_kernel<<<gXbf, blk, 0, stream>>>(x, xbf);
    hipMemsetAsync(cursor, 0, N_NODES * sizeof(int), stream);
    hipMemsetAsync(ctrs, 0, 3 * sizeof(int), stream);
    hist_kernel<<<gEdge, blk, 0, stream>>>(dst, cursor);
    blockscan_kernel<<<SCAN_BLOCKS, 1024, 0, stream>>>(cursor, local, bsums);
    fixup_kernel<<<SCAN_BLOCKS, 1024, 0, stream>>>(local, bsums, offs, cursor);
    fill_kernel<<<gEdge, blk, 0, stream>>>(src, dst, cursor, eidx);

    // layer 0: gather from xbf, write h1
    fused_kernel<1><<<gFus, 512, 0, stream>>>(xbf, offs, eidx, wt, b1, b2, h1, ctrs + 0);
    // layer 1: gather from h1, write h2 (ping-pong: no gather/write race)
    fused_kernel<1><<<gFus, 512, 0, stream>>>(h1, offs, eidx, wt, b1, b2, h2, ctrs + 1);
    // layer 2: gather from h2, write f32 d_out (no relu)
    fused_kernel<2><<<gFus, 512, 0, stream>>>(h2, offs, eidx, wt, b1, b2, (float*)d_out, ctrs + 2);
}

// Round 9
// 572.749 us; speedup vs baseline: 1.1475x; 1.0314x over previous
//
#include <hip/hip_runtime.h>

#define N_NODES 100000
#define N_EDGES 600000
#define DIM 128
#define N_UNITS (N_NODES / 16)  // 6250 16-row units

typedef unsigned short ushortT;
typedef __attribute__((ext_vector_type(8))) short short8;
typedef __attribute__((ext_vector_type(4))) float float4v;
typedef __attribute__((ext_vector_type(4))) unsigned int uint4v;

__device__ __forceinline__ float bf2f(ushortT h) {
    return __builtin_bit_cast(float, ((unsigned int)h) << 16);
}
__device__ __forceinline__ float bflo(unsigned int p) {
    return __builtin_bit_cast(float, p << 16);
}
__device__ __forceinline__ float bfhi(unsigned int p) {
    return __builtin_bit_cast(float, p & 0xffff0000u);
}
__device__ __forceinline__ ushortT f2bf(float f) {  // RNE
    unsigned int x = __builtin_bit_cast(unsigned int, f);
    unsigned int r = (x + 0x7fffu + ((x >> 16) & 1u)) >> 16;
    return (ushortT)r;
}

// ---- prep: W (128x128 f32, KxN) -> transposed + XOR-swizzled bf16 hi/lo images
// element (k,n) stored at  n*128 + (((k>>3) ^ (n&15))<<3) + (k&7)
__global__ __launch_bounds__(256) void prep_kernel(const float* __restrict__ W1,
                                                   const float* __restrict__ W2,
                                                   ushortT* __restrict__ wt) {
    const float* Wf = (blockIdx.x == 0) ? W1 : W2;
    ushortT* outh = wt + blockIdx.x * 32768;
    ushortT* outl = outh + 16384;
    int t = threadIdx.x;
#pragma unroll
    for (int i = 0; i < 16; i++) {
        int c = t + i * 256;            // 0..4095
        int k = c >> 5;
        int n0 = (c & 31) * 4;
        float4v w = *(const float4v*)(Wf + k * 128 + n0);
        int g = k >> 3, kk = k & 7;
#pragma unroll
        for (int j = 0; j < 4; j++) {
            int n = n0 + j;
            ushortT wh = f2bf(w[j]);
            ushortT wl = f2bf(w[j] - bf2f(wh));
            int addr = n * 128 + ((g ^ (n & 15)) << 3) + kk;
            outh[addr] = wh;
            outl[addr] = wl;
        }
    }
}

// ---- x (f32) -> bf16 plane, once per call ----
__global__ __launch_bounds__(256) void xbf_kernel(const float* __restrict__ x,
                                                  ushortT* __restrict__ xb) {
    int i = blockIdx.x * 256 + threadIdx.x;  // 8-elem group; grid exact (6250)
    float4v a = ((const float4v*)x)[2 * i];
    float4v b = ((const float4v*)x)[2 * i + 1];
    ushortT o[8];
#pragma unroll
    for (int j = 0; j < 4; j++) o[j] = f2bf(a[j]);
#pragma unroll
    for (int j = 0; j < 4; j++) o[4 + j] = f2bf(b[j]);
    ((uint4v*)xb)[i] = *(const uint4v*)o;
}

// ---- CSR build ----
__global__ __launch_bounds__(256) void hist_kernel(const int* __restrict__ dst,
                                                   int* __restrict__ counts) {
    int e = blockIdx.x * 256 + threadIdx.x;
    if (e < N_EDGES) atomicAdd(&counts[dst[e]], 1);
}

#define SCAN_BLOCKS 98  // 98*1024 >= 100000

__global__ __launch_bounds__(1024) void blockscan_kernel(const int* __restrict__ counts,
                                                         int* __restrict__ local,
                                                         int* __restrict__ bsums) {
    __shared__ int wsum[16];
    int tid = threadIdx.x, lane = tid & 63, wid = tid >> 6;
    int i = blockIdx.x * 1024 + tid;
    int v = (i < N_NODES) ? counts[i] : 0;
    int incl = v;
#pragma unroll
    for (int off = 1; off < 64; off <<= 1) {
        int u = __shfl_up(incl, off);
        if (lane >= off) incl += u;
    }
    if (lane == 63) wsum[wid] = incl;
    __syncthreads();
    if (wid == 0) {
        int s = (lane < 16) ? wsum[lane] : 0;
#pragma unroll
        for (int off = 1; off < 16; off <<= 1) {
            int u = __shfl_up(s, off);
            if (lane >= off) s += u;
        }
        if (lane < 16) wsum[lane] = s;
    }
    __syncthreads();
    int excl = ((wid == 0) ? 0 : wsum[wid - 1]) + incl - v;
    if (i < N_NODES) local[i] = excl;
    if (tid == 0) bsums[blockIdx.x] = wsum[15];
}

__global__ __launch_bounds__(1024) void fixup_kernel(const int* __restrict__ local,
                                                     const int* __restrict__ bsums,
                                                     int* __restrict__ offsets,
                                                     int* __restrict__ cursor) {
    __shared__ int sbase;
    int tid = threadIdx.x;
    if (tid < 64) {
        int s = 0;
        for (int j = tid; j < blockIdx.x; j += 64) s += bsums[j];
#pragma unroll
        for (int off = 32; off >= 1; off >>= 1) s += __shfl_xor(s, off);
        if (tid == 0) sbase = s;
    }
    __syncthreads();
    int base = sbase;
    int i = blockIdx.x * 1024 + tid;
    if (i < N_NODES) {
        int o = local[i] + base;
        offsets[i] = o;
        cursor[i] = o;
    }
    if (blockIdx.x == 0 && tid == 0) offsets[N_NODES] = N_EDGES;
}

__global__ __launch_bounds__(256) void fill_kernel(const int* __restrict__ src,
                                                   const int* __restrict__ dst,
                                                   int* __restrict__ cursor,
                                                   int* __restrict__ eidx) {
    int e = blockIdx.x * 256 + threadIdx.x;
    if (e < N_EDGES) {
        int pos = atomicAdd(&cursor[dst[e]], 1);
        eidx[pos] = src[e];
    }
}

// lgkm-only wait: vmcnt=63, expcnt=7, lgkmcnt=0 (gfx9 encoding)
#define LGKM0() __builtin_amdgcn_s_waitcnt(0xC07F)

// ---- fused GIN layer: out = act(relu((h + sum_nbr h) @ W1 + b1) @ W2 + b2) ----
// Register-lean 16-ROW units. 768 threads (12 waves), grid 256, 1 block/CU,
// LDS 152KB (all four W images 128KB + 12 x 2KB per-wave scratch) =>
// 3 waves/SIMD at <=170 VGPR (launch_bounds(768) cap; design peak ~130 -> no
// spill, unlike rounds 6/7 which died on the 128-reg cliff).
// Barrier-free persistent: one __syncthreads after W staging, then waves pop
// 16-row units off a global atomic (balance + desync; round-7-proven).
// Gather: 2-edge batches, next-batch eidx prefetched before accumulate (breaks the
// eidx->row serial chain at +4 regs). Accumulation order: self, then edges
// ascending == original agg_kernel => bit-identical. GEMM B-frags loaded 8 at a
// time (bh then bl; per-acc[n] MFMA order unchanged => bit-identical).
// OUT 1: bf16 plane (stride 128) + relu.  OUT 2: f32 (stride 128), no relu.
template <int OUT>
__global__ __launch_bounds__(768) void fused_kernel(const ushortT* __restrict__ Hprev,
                                                    const int* __restrict__ offs,
                                                    const int* __restrict__ eidx,
                                                    const ushortT* __restrict__ wtAll,
                                                    const float* __restrict__ b1,
                                                    const float* __restrict__ b2,
                                                    void* __restrict__ out,
                                                    int* __restrict__ ctr) {
    __shared__ ushortT SH[77824];  // 155648B: W1H|W1L|W2H|W2L [0,65536) ushorts, scratch [65536,77824)

    int t = threadIdx.x, lane = t & 63, wid = t >> 6;  // wid 0..11
    int quad = lane >> 4, col16 = lane & 15;

    float bia1[8], bia2[8];
#pragma unroll
    for (int n = 0; n < 8; n++) {
        bia1[n] = b1[n * 16 + col16];
        bia2[n] = b2[n * 16 + col16];
    }

    // stage all four W images (128KB), once
    for (int i = t; i < 8192; i += 768)
        ((uint4v*)SH)[i] = ((const uint4v*)wtAll)[i];
    __syncthreads();  // the only block-wide barrier

    ushortT* scr = &SH[65536 + wid * 1024];  // 2KB per-wave scratch (16 rows x 64 ushorts)

    for (;;) {
        int u = 0;
        if (lane == 0) u = atomicAdd(ctr, 1);
        u = __builtin_amdgcn_readfirstlane(u);
        if (u >= N_UNITS) break;
        int row0 = u * 16;

        // ---- fused aggregation -> A fragments (ah/al) ----
        int v = row0 + col16;
        const ushortT* hq = Hprev + (size_t)v * DIM + quad * 8;
        short8 sf[4];
#pragma unroll
        for (int s = 0; s < 4; s++) sf[s] = *(const short8*)(hq + s * 32);
        int beg = offs[v];
        int cnt = offs[v + 1] - beg;
        float accf[4][8];
#pragma unroll
        for (int s = 0; s < 4; s++) {  // self term first (same order as agg_kernel)
            uint4v uu = __builtin_bit_cast(uint4v, sf[s]);
#pragma unroll
            for (int p = 0; p < 4; p++) {
                accf[s][2 * p]     = bflo(uu[p]);
                accf[s][2 * p + 1] = bfhi(uu[p]);
            }
        }
        int nb = (cnt + 1) >> 1;  // 2-edge batches
        int iC0 = 0, iC1 = 0;
        if (nb > 0) {
            iC0 = eidx[beg];
            int q1 = (1 > cnt - 1) ? cnt - 1 : 1;
            iC1 = eidx[beg + q1];
        }
        for (int b = 0; b < nb; b++) {
            short8 v0[4], v1[4];
            const ushortT* h0 = Hprev + (size_t)iC0 * DIM + quad * 8;
            const ushortT* h1p = Hprev + (size_t)iC1 * DIM + quad * 8;
#pragma unroll
            for (int s = 0; s < 4; s++) {
                v0[s] = *(const short8*)(h0 + s * 32);
                v1[s] = *(const short8*)(h1p + s * 32);
            }
            if (b + 1 < nb) {  // prefetch next indices (overlaps row latency)
                int q0 = 2 * b + 2, q1 = 2 * b + 3;
                if (q1 > cnt - 1) q1 = cnt - 1;
                iC0 = eidx[beg + q0];
                iC1 = eidx[beg + q1];
            }
            int rem = cnt - 2 * b;  // >=1
#pragma unroll
            for (int s = 0; s < 4; s++) {
                uint4v uu = __builtin_bit_cast(uint4v, v0[s]);
#pragma unroll
                for (int p = 0; p < 4; p++) {
                    accf[s][2 * p]     += bflo(uu[p]);
                    accf[s][2 * p + 1] += bfhi(uu[p]);
                }
            }
            if (rem >= 2) {
#pragma unroll
                for (int s = 0; s < 4; s++) {
                    uint4v uu = __builtin_bit_cast(uint4v, v1[s]);
#pragma unroll
                    for (int p = 0; p < 4; p++) {
                        accf[s][2 * p]     += bflo(uu[p]);
                        accf[s][2 * p + 1] += bfhi(uu[p]);
                    }
                }
            }
        }
        // RNE hi/lo split -> MFMA A fragments (identical to old z hi/lo planes)
        short8 ah[4], al[4];
#pragma unroll
        for (int s = 0; s < 4; s++) {
            ushortT oh[8], ol[8];
#pragma unroll
            for (int e = 0; e < 8; e++) {
                ushortT hi = f2bf(accf[s][e]);
                oh[e] = hi;
                ol[e] = f2bf(accf[s][e] - bf2f(hi));
            }
            ah[s] = *(const short8*)oh;
            al[s] = *(const short8*)ol;
        }

        // ---- GEMM1: acc = z @ W1 (3-term bf16 split; B loaded 8 frags at a time) ----
        float4v acc[8];
#pragma unroll
        for (int n = 0; n < 8; n++) acc[n] = (float4v)0.0f;
#pragma unroll
        for (int s = 0; s < 4; s++) {
            int sw = ((s * 4 + quad) ^ col16) << 3;
            short8 bh[8];
#pragma unroll
            for (int n = 0; n < 8; n++) bh[n] = *(const short8*)&SH[(n * 16 + col16) * 128 + sw];
            __builtin_amdgcn_s_setprio(1);
#pragma unroll
            for (int n = 0; n < 8; n++) {
                acc[n] = __builtin_amdgcn_mfma_f32_16x16x32_bf16(ah[s], bh[n], acc[n], 0, 0, 0);
                acc[n] = __builtin_amdgcn_mfma_f32_16x16x32_bf16(al[s], bh[n], acc[n], 0, 0, 0);
            }
            __builtin_amdgcn_s_setprio(0);
            short8 bl[8];
#pragma unroll
            for (int n = 0; n < 8; n++) bl[n] = *(const short8*)&SH[16384 + (n * 16 + col16) * 128 + sw];
            __builtin_amdgcn_s_setprio(1);
#pragma unroll
            for (int n = 0; n < 8; n++)
                acc[n] = __builtin_amdgcn_mfma_f32_16x16x32_bf16(ah[s], bl[n], acc[n], 0, 0, 0);
            __builtin_amdgcn_s_setprio(0);
        }

        // ---- transpose (per-wave scratch) + GEMM2 ----
        float4v acc2[8];
#pragma unroll
        for (int n = 0; n < 8; n++) acc2[n] = (float4v)0.0f;
#pragma unroll
        for (int s2 = 0; s2 < 4; s2++) {
            LGKM0();  // WAR: prior scratch reads landed before overwrite
#pragma unroll
            for (int h = 0; h < 2; h++) {
                int n = s2 * 2 + h;
#pragma unroll
                for (int i = 0; i < 4; i++) {
                    float vv = acc[n][i] + bia1[n];
                    vv = vv > 0.0f ? vv : 0.0f;
                    int row = quad * 4 + i;
                    ushortT hi = f2bf(vv);
                    ushortT lo = f2bf(vv - bf2f(hi));
                    int c8 = h * 2 + (col16 >> 3);
                    int base = row * 64 + (col16 & 7);
                    scr[base + ((c8 ^ (row & 7)) << 3)]       = hi;
                    scr[base + (((4 + c8) ^ (row & 7)) << 3)] = lo;
                }
            }
            LGKM0();  // writes visible before readback (per-wave scratch)
            short8 a2h = *(const short8*)&scr[col16 * 64 + ((quad ^ (col16 & 7)) << 3)];
            short8 a2l = *(const short8*)&scr[col16 * 64 + (((4 + quad) ^ (col16 & 7)) << 3)];
            int sw = ((s2 * 4 + quad) ^ col16) << 3;
            short8 bh[8];
#pragma unroll
            for (int n = 0; n < 8; n++) bh[n] = *(const short8*)&SH[32768 + (n * 16 + col16) * 128 + sw];
            __builtin_amdgcn_s_setprio(1);
#pragma unroll
            for (int n = 0; n < 8; n++) {
                acc2[n] = __builtin_amdgcn_mfma_f32_16x16x32_bf16(a2h, bh[n], acc2[n], 0, 0, 0);
                acc2[n] = __builtin_amdgcn_mfma_f32_16x16x32_bf16(a2l, bh[n], acc2[n], 0, 0, 0);
            }
            __builtin_amdgcn_s_setprio(0);
            short8 bl[8];
#pragma unroll
            for (int n = 0; n < 8; n++) bl[n] = *(const short8*)&SH[49152 + (n * 16 + col16) * 128 + sw];
            __builtin_amdgcn_s_setprio(1);
#pragma unroll
            for (int n = 0; n < 8; n++)
                acc2[n] = __builtin_amdgcn_mfma_f32_16x16x32_bf16(a2h, bl[n], acc2[n], 0, 0, 0);
            __builtin_amdgcn_s_setprio(0);
        }

        // ---- epilogue: 4-row passes through the 2KB scratch, coalesced stores ----
        // C/D layout: col = n*16+col16, row = quad*4 + i
        LGKM0();  // GEMM2's last scratch reads done before epilogue overwrites
        if constexpr (OUT == 1) {
#pragma unroll
            for (int i = 0; i < 4; i++) {
#pragma unroll
                for (int n = 0; n < 8; n++) {
                    float vv = acc2[n][i] + bia2[n];
                    vv = vv > 0.0f ? vv : 0.0f;
                    scr[quad * 136 + n * 16 + col16] = f2bf(vv);
                }
                LGKM0();
                uint4v val = *(const uint4v*)&scr[(lane >> 4) * 136 + (lane & 15) * 8];
                *(uint4v*)((ushortT*)out +
                           (size_t)(row0 + (lane >> 4) * 4 + i) * 128 + (lane & 15) * 8) = val;
                LGKM0();  // WAR before next pass overwrites scratch
            }
        } else {
            float* trf = (float*)scr;  // 4 rows x 68 floats = 1088B <= 2KB
#pragma unroll
            for (int i = 0; i < 4; i++)
#pragma unroll
                for (int nh = 0; nh < 2; nh++) {
#pragma unroll
                    for (int k = 0; k < 4; k++) {
                        int n = nh * 4 + k;
                        trf[quad * 68 + k * 16 + col16] = acc2[n][i] + bia2[n];
                    }
                    LGKM0();
                    float4v val = *(const float4v*)&trf[(lane >> 4) * 68 + (lane & 15) * 4];
                    *(float4v*)((float*)out +
                                (size_t)(row0 + (lane >> 4) * 4 + i) * 128 +
                                nh * 64 + (lane & 15) * 4) = val;
                    LGKM0();
                }
        }
    }
}

extern "C" void kernel_launch(void* const* d_in, const int* in_sizes, int n_in,
                              void* d_out, int out_size, void* d_ws, size_t ws_size,
                              hipStream_t stream) {
    const float* x  = (const float*)d_in[0];
    const int* src  = (const int*)d_in[1];
    const int* dst  = (const int*)d_in[2];
    const float* W1 = (const float*)d_in[3];
    const float* b1 = (const float*)d_in[4];
    const float* W2 = (const float*)d_in[5];
    const float* b2 = (const float*)d_in[6];

    char* ws = (char*)d_ws;
    ushortT* wt     = (ushortT*)ws;                        // 128 KB: W1H|W1L|W2H|W2L (swizzled)
    int*     offs   = (int*)(ws + 131072);                 // 100001 ints
    int*     cursor = (int*)(ws + 531456);                 // 100000 ints
    int*     eidx   = (int*)(ws + 931456);                 // 600000 ints
    int*     local  = (int*)(ws + 3331456);                // 100000 ints
    int*     bsums  = (int*)(ws + 3731456);                // 98 ints (ends 3731848)
    int*     ctrs   = (int*)(ws + 3731848);                // 3 ints (unit pop counters)
    ushortT* xbf    = (ushortT*)(ws + 3731968);            // 25.6 MB bf16 x
    ushortT* h1     = (ushortT*)(ws + 3731968 + 25600000); // 25.6 MB bf16 h (layer0 out)
    ushortT* h2     = (ushortT*)(ws + 3731968 + 51200000); // 25.6 MB bf16 h (layer1 out)
    // total ~80.5 MB

    dim3 blk(256);
    const int gEdge = (N_EDGES + 255) / 256;    // 2344
    const int gXbf  = N_NODES * DIM / 8 / 256;  // 6250 exact
    const int gFus  = 256;                      // persistent: 1 block/CU, 12 waves

    prep_kernel<<<2, blk, 0, stream>>>(W1, W2, wt);
    xbf_kernel<<<gXbf, blk, 0, stream>>>(x, xbf);
    hipMemsetAsync(cursor, 0, N_NODES * sizeof(int), stream);
    hipMemsetAsync(ctrs, 0, 3 * sizeof(int), stream);
    hist_kernel<<<gEdge, blk, 0, stream>>>(dst, cursor);
    blockscan_kernel<<<SCAN_BLOCKS, 1024, 0, stream>>>(cursor, local, bsums);
    fixup_kernel<<<SCAN_BLOCKS, 1024, 0, stream>>>(local, bsums, offs, cursor);
    fill_kernel<<<gEdge, blk, 0, stream>>>(src, dst, cursor, eidx);

    // layer 0: gather from xbf, write h1
    fused_kernel<1><<<gFus, 768, 0, stream>>>(xbf, offs, eidx, wt, b1, b2, h1, ctrs + 0);
    // layer 1: gather from h1, write h2 (ping-pong: no gather/write race)
    fused_kernel<1><<<gFus, 768, 0, stream>>>(h1, offs, eidx, wt, b1, b2, h2, ctrs + 1);
    // layer 2: gather from h2, write f32 d_out (no relu)
    fused_kernel<2><<<gFus, 768, 0, stream>>>(h2, offs, eidx, wt, b1, b2, (float*)d_out, ctrs + 2);
}